// Round 11
// baseline (110.139 us; speedup 1.0000x reference)
//
#include <hip/hip_runtime.h>

// Sparse submanifold 3D conv via dense bf16 MFMA (32x32x16). Round 11:
// OCCUPANCY 2x: R10 was latency-bound with every pipe <30% busy and only 16
// waves/CU (LDS 108KB -> 1 block/CU). This round:
//  - LDS holds HALF the k-range (56KB): stage k0..13, loop, barrier, restage
//    k14..26, loop. 2 blocks/CU now fit in LDS.
//  - VGPR <=64 (required for 32 waves/CU): co-half split (wave pair shares a
//    32-row tile; each wave computes one 32-col output half -> acc 16 regs),
//    nbr preloaded per-half (14 ints), A-gather pipeline depth-1 even/odd
//    (16 regs). __launch_bounds__(1024, 8) enforces the cap.
//  - Kept: bf16 feature pre-pass (d_ws), OOB-returning SRSRC gathers
//    (sentinel -> HW zeros), XCD-contiguous swizzle, conflict-free
//    fragment-ordered W->LDS staging, static register indexing throughout.
//  - Fallback (ws too small): R9/R10 f32-gather kernel, verified.

typedef short          bf16x8 __attribute__((ext_vector_type(8)));
typedef unsigned short u16x8  __attribute__((ext_vector_type(8)));
typedef float          f32x16 __attribute__((ext_vector_type(16)));
typedef float          f32x4a __attribute__((ext_vector_type(4)));
typedef int            i32x4  __attribute__((ext_vector_type(4)));
typedef int            i32x4u __attribute__((ext_vector_type(4), aligned(4)));
typedef int            i32x2u __attribute__((ext_vector_type(2), aligned(4)));

constexpr int CIN  = 32;
constexpr int COUT = 64;
constexpr int KV   = 27;
constexpr int KVH1 = 14, KVH2 = 13;    // k's per LDS-resident half
constexpr int RPW  = 32;               // rows per wave-pair tile
constexpr int TPB  = 8;                // tiles per 1024-thread block
constexpr int RPB  = TPB * RPW;        // 256 rows per block
constexpr int FRH  = KVH1 * 4;         // max fragments per half = 56

// ---- asm helpers ----
// 2 x buffer_load_dwordx4: one lane's 32B (16 bf16) share of a feature row.
// chunk0 (ci 0..15) at voff+0, chunk1 (ci 16..31) at voff+32. OOB -> 0.
#define LOADD(g0, g1, voff, rs)                                           \
    asm volatile("buffer_load_dwordx4 %0, %2, %3, 0 offen offset:0\n\t"   \
                 "buffer_load_dwordx4 %1, %2, %3, 0 offen offset:32"      \
                 : "=&v"(g0), "=&v"(g1)                                   \
                 : "v"(voff), "s"(rs))
#define WAIT2(a, b) asm volatile("s_waitcnt vmcnt(2)" : "+v"(a), "+v"(b))
#define WAIT0(a, b) asm volatile("s_waitcnt vmcnt(0)" : "+v"(a), "+v"(b))

// f32 variants (fallback kernel)
#define LOADQ(g0, g1, g2, g3, voff, rs)                                   \
    asm volatile("buffer_load_dwordx4 %0, %4, %5, 0 offen offset:0\n\t"   \
                 "buffer_load_dwordx4 %1, %4, %5, 0 offen offset:16\n\t"  \
                 "buffer_load_dwordx4 %2, %4, %5, 0 offen offset:64\n\t"  \
                 "buffer_load_dwordx4 %3, %4, %5, 0 offen offset:80"      \
                 : "=&v"(g0), "=&v"(g1), "=&v"(g2), "=&v"(g3)             \
                 : "v"(voff), "s"(rs))
#define WAITV4(a, b, c, d) \
    asm volatile("s_waitcnt vmcnt(4)" : "+v"(a), "+v"(b), "+v"(c), "+v"(d))
#define WAITV0(a, b, c, d) \
    asm volatile("s_waitcnt vmcnt(0)" : "+v"(a), "+v"(b), "+v"(c), "+v"(d))

__device__ inline bf16x8 cvt8(f32x4a lo, f32x4a hi) {
    bf16x8 r;
#pragma unroll
    for (int j = 0; j < 4; ++j) {
        r[j]     = __builtin_bit_cast(short, (__bf16)lo[j]);
        r[4 + j] = __builtin_bit_cast(short, (__bf16)hi[j]);
    }
    return r;
}

// ---- pre-pass: features f32 -> bf16 into workspace ----
__global__ __launch_bounds__(256)
void feats_to_bf16(const float* __restrict__ in,
                   unsigned short* __restrict__ outp, int ngroups)
{
    int i = blockIdx.x * 256 + threadIdx.x;
    const int stride = gridDim.x * 256;
    for (; i < ngroups; i += stride) {
        const f32x4a a = *(const f32x4a*)(in + (size_t)i * 8);
        const f32x4a b = *(const f32x4a*)(in + (size_t)i * 8 + 4);
        u16x8 t;
#pragma unroll
        for (int j = 0; j < 4; ++j) {
            t[j]     = __builtin_bit_cast(unsigned short, (__bf16)a[j]);
            t[4 + j] = __builtin_bit_cast(unsigned short, (__bf16)b[j]);
        }
        *(u16x8*)(outp + (size_t)i * 8) = t;
    }
}

// stage k's [k0, k0+nk) of W (f32 [k][ci][co]) into wlds, fragment-ordered
// bf16, linear b128 writes. frag_local = klocal*4 + cc*2 + h.
#define STAGE_HALF(k0, nk)                                                  \
    do {                                                                    \
        _Pragma("unroll")                                                   \
        for (int i_ = 0; i_ < 4; ++i_) {                                    \
            const int s_ = tid + 1024 * i_;                                 \
            if (s_ < (nk) * 256) {                                          \
                const int fl_ = s_ >> 6;                                    \
                const int ln_ = s_ & 63;                                    \
                const int k_  = (k0) + (fl_ >> 2);                          \
                const int cc_ = (fl_ >> 1) & 1;                             \
                const int h_  = fl_ & 1;                                    \
                const int co_ = (ln_ & 31) + (h_ << 5);                     \
                const int ci_ = (cc_ << 4) + ((ln_ >> 5) << 3);             \
                const float* src_ = weight + k_ * 2048 + ci_ * 64 + co_;    \
                u16x8 t_;                                                   \
                _Pragma("unroll")                                           \
                for (int j_ = 0; j_ < 8; ++j_)                              \
                    t_[j_] = __builtin_bit_cast(unsigned short,             \
                                                (__bf16)src_[j_ * 64]);     \
                *(u16x8*)&wlds[s_ * 8] = t_;                                \
            }                                                               \
        }                                                                   \
    } while (0)

// neighbor-index accessor for the current 14-slot window (j literal -> folds)
#define NJ(j) ((j) < 4 ? m0[(j) & 3] : (j) < 8 ? m1[(j) & 3]                \
             : (j) < 12 ? m2[(j) & 3] : ((j) == 12 ? mA : mB2))

// one k-half: per-half nbr preload, depth-1 even/odd gather pipeline,
// 2 MFMA per k (cc chunks) into this wave's co-half accumulator.
#define HALF_PASS(K0, NK)                                                   \
    do {                                                                    \
        const int* pk = p + (K0);                                           \
        i32x4u m0 = *(const i32x4u*)(pk);                                   \
        i32x4u m1 = *(const i32x4u*)(pk + 4);                               \
        i32x4u m2 = *(const i32x4u*)(pk + 8);                               \
        int mA  = pk[12];                                                   \
        int mB2 = ((NK) == 14) ? pk[13] : 0;                                \
        if (!rv) {                                                          \
            m0 = i32x4u{n, n, n, n}; m1 = m0; m2 = m0; mA = n; mB2 = n;     \
        }                                                                   \
        bf16x8 ea, eb, oa, ob;                                              \
        { const int vo_ = (NJ(0) << 6) + (e5 << 4);                         \
          LOADD(ea, eb, vo_, rsrc); }                                       \
        _Pragma("unroll")                                                   \
        for (int j = 0; j < (NK); ++j) {                                    \
            const int fb = (((j << 2) | h) << 9) + lane * 8;                \
            const bf16x8 b0 = *(const bf16x8*)&wlds[fb];                    \
            const bf16x8 b1 = *(const bf16x8*)&wlds[fb + 1024];             \
            bf16x8 x0, x1;                                                  \
            if ((j & 1) == 0) {                                             \
                if (j + 1 < (NK)) {                                         \
                    const int vo_ = (NJ(j + 1) << 6) + (e5 << 4);           \
                    LOADD(oa, ob, vo_, rsrc); WAIT2(ea, eb);                \
                } else WAIT0(ea, eb);                                       \
                x0 = ea; x1 = eb;                                           \
            } else {                                                        \
                if (j + 1 < (NK)) {                                         \
                    const int vo_ = (NJ(j + 1) << 6) + (e5 << 4);           \
                    LOADD(ea, eb, vo_, rsrc); WAIT2(oa, ob);                \
                } else WAIT0(oa, ob);                                       \
                x0 = oa; x1 = ob;                                           \
            }                                                               \
            acc = __builtin_amdgcn_mfma_f32_32x32x16_bf16(x0, b0, acc, 0, 0, 0); \
            acc = __builtin_amdgcn_mfma_f32_32x32x16_bf16(x1, b1, acc, 0, 0, 0); \
        }                                                                   \
    } while (0)

// ---- main kernel: bf16 gathers, 56KB LDS (k time-multiplexed), co-half
//      split wave pairs, target 2 blocks/CU ----
__global__ __launch_bounds__(1024, 8)
void spconv_mfma_bf16(const unsigned short* __restrict__ fbf16,
                      const float* __restrict__ weight,
                      const float* __restrict__ bias,
                      const int*   __restrict__ nbr,
                      float*       __restrict__ out,
                      int n, int nwg)
{
    __shared__ __align__(16) unsigned short wlds[FRH * 512];  // 56 KiB

    const int tid  = threadIdx.x;
    const int lane = tid & 63;
    const int wv   = tid >> 6;
    const int l31  = lane & 31;
    const int e5   = lane >> 5;
    const int h    = wv & 1;               // co-half this wave produces
    const int tile = wv >> 1;              // row-tile shared by the pair

    STAGE_HALF(0, KVH1);
    __syncthreads();

    // XCD-contiguous block swizzle (bijective for any nwg)
    const int q    = nwg >> 3, r = nwg & 7;
    const int xcd  = blockIdx.x & 7, bidx = blockIdx.x >> 3;
    const int wg   = (xcd < r ? xcd * (q + 1) : r * (q + 1) + (xcd - r) * q) + bidx;

    const int rb = wg * RPB + tile * RPW;  // NO early return: all waves must
                                           // reach the restage barriers.

    // SRSRC over bf16 features: 64 B/row; sentinel row n -> OOB -> zeros
    i32x4 rsrc;
    rsrc.x = (int)(unsigned)(uintptr_t)fbf16;
    rsrc.y = (int)((uintptr_t)fbf16 >> 32);
    rsrc.z = n * (int)(CIN * sizeof(unsigned short));
    rsrc.w = 0x00020000;

    const int  row = rb + l31;
    const bool rv  = row < n;
    const int* p   = nbr + (size_t)min(row, n - 1) * KV;

    f32x16 acc = {};                       // this wave's co-half

    HALF_PASS(0, KVH1);
    __syncthreads();
    STAGE_HALF(KVH1, KVH2);
    __syncthreads();
    HALF_PASS(KVH1, KVH2);

    // epilogue: C/D layout col=lane&31, row=(t&3)+8*(t>>2)+4*e5
    const float bb = bias[l31 + (h << 5)];
    const int   co = l31 + (h << 5);
#pragma unroll
    for (int t = 0; t < 16; ++t) {
        const int rr   = (t & 3) + ((t >> 2) << 3) + (e5 << 2);
        const int orow = rb + rr;
        if (orow < n) out[(size_t)orow * COUT + co] = acc[t] + bb;
    }
}

// ---- fallback kernel (R9, verified): f32 gathers, full 108KB LDS ----
constexpr int NFRAG_FB = KV * 4;
constexpr int SLOTS_FB = NFRAG_FB * 64;

#define NIDX(A, B, C, k) ((k) < 24 ? (A)[(k) >> 2][(k) & 3] \
                                   : ((k) < 26 ? (B)[(k) - 24] : (C)))

__global__ __launch_bounds__(1024, 4)
void spconv_mfma_f32g(const float* __restrict__ feats,
                      const float* __restrict__ weight,
                      const float* __restrict__ bias,
                      const int*   __restrict__ nbr,
                      float*       __restrict__ out,
                      int n, int nwg)
{
    __shared__ __align__(16) unsigned short wlds[NFRAG_FB * 512];  // 108 KiB

    const int tid  = threadIdx.x;
    const int lane = tid & 63;
    const int wv   = tid >> 6;
    const int l31  = lane & 31;
    const int e5   = lane >> 5;

#pragma unroll
    for (int i = 0; i < 7; ++i) {
        const int s = tid + 1024 * i;
        if (s < SLOTS_FB) {
            const int frag = s >> 6;
            const int ln   = s & 63;
            const int k    = frag >> 2;
            const int cc   = (frag >> 1) & 1;
            const int hh   = frag & 1;
            const int co   = (ln & 31) + (hh << 5);
            const int cib  = (cc << 4) + ((ln >> 5) << 3);
            const float* src = weight + k * 2048 + cib * 64 + co;
            u16x8 t;
#pragma unroll
            for (int j = 0; j < 8; ++j)
                t[j] = __builtin_bit_cast(unsigned short, (__bf16)src[j * 64]);
            *(u16x8*)&wlds[s * 8] = t;
        }
    }
    __syncthreads();

    const int q    = nwg >> 3, r = nwg & 7;
    const int xcd  = blockIdx.x & 7, bidx = blockIdx.x >> 3;
    const int wg   = (xcd < r ? xcd * (q + 1) : r * (q + 1) + (xcd - r) * q) + bidx;

    const int rb = wg * 512 + wv * 32;
    if (rb >= n) return;

    i32x4 rsrc;
    rsrc.x = (int)(unsigned)(uintptr_t)feats;
    rsrc.y = (int)((uintptr_t)feats >> 32);
    rsrc.z = n * (int)(CIN * sizeof(float));
    rsrc.w = 0x00020000;

    const int  row = rb + l31;
    const bool rv  = row < n;
    const int* pp  = nbr + (size_t)min(row, n - 1) * KV;
    i32x4u nA[6]; i32x2u nB; int nC;
#pragma unroll
    for (int qq = 0; qq < 6; ++qq) nA[qq] = *(const i32x4u*)(pp + 4 * qq);
    nB = *(const i32x2u*)(pp + 24);
    nC = pp[26];
    if (!rv) {
#pragma unroll
        for (int qq = 0; qq < 6; ++qq) nA[qq] = i32x4u{n, n, n, n};
        nB = i32x2u{n, n};
        nC = n;
    }

    f32x16 acc0 = {}, acc1 = {};

#define GATHER_K(kk, B0, B1, B2, B3)                                      \
    do {                                                                  \
        const int voff_ = (NIDX(nA, nB, nC, (kk)) << 7) + (e5 << 5);      \
        LOADQ(B0, B1, B2, B3, voff_, rsrc);                               \
    } while (0)

    f32x4a pa0, pa1, pa2, pa3, pb0, pb1, pb2, pb3;
    GATHER_K(0, pa0, pa1, pa2, pa3);
#pragma unroll
    for (int k = 0; k < KV; ++k) {
        const int fb = (k << 2) * 512 + lane * 8;
        const bf16x8 b00 = *(const bf16x8*)&wlds[fb];
        const bf16x8 b01 = *(const bf16x8*)&wlds[fb + 512];
        const bf16x8 b10 = *(const bf16x8*)&wlds[fb + 1024];
        const bf16x8 b11 = *(const bf16x8*)&wlds[fb + 1536];

        bf16x8 x0, x1;
        if ((k & 1) == 0) {
            if (k + 1 < KV) { GATHER_K(k + 1, pb0, pb1, pb2, pb3); WAITV4(pa0, pa1, pa2, pa3); }
            else            { WAITV0(pa0, pa1, pa2, pa3); }
            x0 = cvt8(pa0, pa1); x1 = cvt8(pa2, pa3);
        } else {
            if (k + 1 < KV) { GATHER_K(k + 1, pa0, pa1, pa2, pa3); WAITV4(pb0, pb1, pb2, pb3); }
            else            { WAITV0(pb0, pb1, pb2, pb3); }
            x0 = cvt8(pb0, pb1); x1 = cvt8(pb2, pb3);
        }

        acc0 = __builtin_amdgcn_mfma_f32_32x32x16_bf16(x0, b00, acc0, 0, 0, 0);
        acc1 = __builtin_amdgcn_mfma_f32_32x32x16_bf16(x0, b01, acc1, 0, 0, 0);
        acc0 = __builtin_amdgcn_mfma_f32_32x32x16_bf16(x1, b10, acc0, 0, 0, 0);
        acc1 = __builtin_amdgcn_mfma_f32_32x32x16_bf16(x1, b11, acc1, 0, 0, 0);
    }
#undef GATHER_K

    const float bb0 = bias[l31];
    const float bb1 = bias[l31 + 32];
#pragma unroll
    for (int t = 0; t < 16; ++t) {
        const int rr   = (t & 3) + ((t >> 2) << 3) + (e5 << 2);
        const int orow = rb + rr;
        if (orow < n) {
            out[(size_t)orow * COUT + l31]      = acc0[t] + bb0;
            out[(size_t)orow * COUT + l31 + 32] = acc1[t] + bb1;
        }
    }
}

extern "C" void kernel_launch(void* const* d_in, const int* in_sizes, int n_in,
                              void* d_out, int out_size, void* d_ws, size_t ws_size,
                              hipStream_t stream)
{
    const float* feats  = (const float*)d_in[0];   // (N, 32) f32
    const float* weight = (const float*)d_in[1];   // (27, 32, 64) f32
    const float* bias   = (const float*)d_in[2];   // (64,) f32
    const int*   nbr    = (const int*)  d_in[3];   // (N, 27) i32, sentinel = N

    float* out = (float*)d_out;                    // (N, 64) f32

    const int n = in_sizes[0] / CIN;

    const size_t need = (size_t)n * CIN * sizeof(unsigned short);
    if (ws_size >= need) {
        unsigned short* fbf16 = (unsigned short*)d_ws;
        const int ngroups = n * CIN / 8;
        feats_to_bf16<<<dim3(2048), dim3(256), 0, stream>>>(feats, fbf16, ngroups);
        const int nwg = (n + RPB - 1) / RPB;
        spconv_mfma_bf16<<<dim3(nwg), dim3(1024), 0, stream>>>(
            fbf16, weight, bias, nbr, out, n, nwg);
    } else {
        const int nwg = (n + 511) / 512;
        spconv_mfma_f32g<<<dim3(nwg), dim3(1024), 0, stream>>>(
            feats, weight, bias, nbr, out, n, nwg);
    }
}

// Round 12
// 83.795 us; speedup vs baseline: 1.3144x; 1.3144x over previous
//
#include <hip/hip_runtime.h>

// Sparse submanifold 3D conv via dense bf16 MFMA (32x32x16). Round 12:
// REVERT R11 (co-half split duplicated gather+nbr traffic: FETCH 40->92MB,
// 83->110us). Base = R10 (83us) + ONE change:
//  - B-FRAGMENT REGISTER DOUBLE-BUFFER: R10 issued the 4 ds_read_b128 for
//    W[k] in the same k-body that consumes them -> compiler emits lgkmcnt
//    right before the first MFMA = ~120cyc LDS-latency stall per body
//    (VGPR=56 proved no cross-body pipelining). Now body k issues k+1's
//    fragments into a static even/odd register pair and MFMAs consume data
//    issued a full body (~200cyc) earlier -> lgkm stall ~0. +32 VGPR, free
//    (LDS 108KB caps at 1 block/CU; budget 128).
//  - Kept from R10: bf16 feature pre-pass (d_ws), OOB-returning SRSRC
//    gathers (sentinel row n -> HW zeros), depth-3 A-gather pipeline with
//    static mod-4 stages + data-tied counted vmcnt, XCD-contiguous swizzle,
//    conflict-free fragment-ordered W->LDS prologue, static acc indexing.
//  - Fallback (ws too small): R9 f32-gather kernel, verified.

typedef short          bf16x8 __attribute__((ext_vector_type(8)));
typedef unsigned short u16x8  __attribute__((ext_vector_type(8)));
typedef float          f32x16 __attribute__((ext_vector_type(16)));
typedef float          f32x4a __attribute__((ext_vector_type(4)));
typedef int            i32x4  __attribute__((ext_vector_type(4)));
typedef int            i32x4u __attribute__((ext_vector_type(4), aligned(4)));
typedef int            i32x2u __attribute__((ext_vector_type(2), aligned(4)));

constexpr int CIN   = 32;
constexpr int COUT  = 64;
constexpr int KV    = 27;
constexpr int WAVES = 16;
constexpr int RPW   = 32;              // rows per wave (one 32x32 tile)
constexpr int RPB   = WAVES * RPW;     // 512 rows per block
constexpr int NFRAG = KV * 4;          // B fragments (k * {ci-chunk} * {co-half})
constexpr int SLOTS = NFRAG * 64;      // 6912 b128 LDS slots

// ---- asm helpers ----
// 2 x buffer_load_dwordx4: one lane's 32B (16 bf16) share of a feature row.
// chunk0 (ci 0..15) at voff+0, chunk1 (ci 16..31) at voff+32. OOB -> 0.
#define LOADD(g0, g1, voff, rs)                                           \
    asm volatile("buffer_load_dwordx4 %0, %2, %3, 0 offen offset:0\n\t"   \
                 "buffer_load_dwordx4 %1, %2, %3, 0 offen offset:32"      \
                 : "=&v"(g0), "=&v"(g1)                                   \
                 : "v"(voff), "s"(rs))
// counted waits, data-tied to the consumed stage registers (no hoisting)
#define WAIT6(a, b) asm volatile("s_waitcnt vmcnt(6)" : "+v"(a), "+v"(b))
#define WAIT4(a, b) asm volatile("s_waitcnt vmcnt(4)" : "+v"(a), "+v"(b))
#define WAIT2(a, b) asm volatile("s_waitcnt vmcnt(2)" : "+v"(a), "+v"(b))
#define WAIT0(a, b) asm volatile("s_waitcnt vmcnt(0)" : "+v"(a), "+v"(b))

// f32 variant (fallback kernel)
#define LOADQ(g0, g1, g2, g3, voff, rs)                                   \
    asm volatile("buffer_load_dwordx4 %0, %4, %5, 0 offen offset:0\n\t"   \
                 "buffer_load_dwordx4 %1, %4, %5, 0 offen offset:16\n\t"  \
                 "buffer_load_dwordx4 %2, %4, %5, 0 offen offset:64\n\t"  \
                 "buffer_load_dwordx4 %3, %4, %5, 0 offen offset:80"      \
                 : "=&v"(g0), "=&v"(g1), "=&v"(g2), "=&v"(g3)             \
                 : "v"(voff), "s"(rs))
#define WAITV4(a, b, c, d) \
    asm volatile("s_waitcnt vmcnt(4)" : "+v"(a), "+v"(b), "+v"(c), "+v"(d))
#define WAITV0(a, b, c, d) \
    asm volatile("s_waitcnt vmcnt(0)" : "+v"(a), "+v"(b), "+v"(c), "+v"(d))

__device__ inline bf16x8 cvt8(f32x4a lo, f32x4a hi) {
    bf16x8 r;
#pragma unroll
    for (int j = 0; j < 4; ++j) {
        r[j]     = __builtin_bit_cast(short, (__bf16)lo[j]);
        r[4 + j] = __builtin_bit_cast(short, (__bf16)hi[j]);
    }
    return r;
}

// static-index accessor into the preloaded nbr registers (folds after unroll)
#define NIDX(A, B, C, k) ((k) < 24 ? (A)[(k) >> 2][(k) & 3] \
                                   : ((k) < 26 ? (B)[(k) - 24] : (C)))

// ---- pre-pass: features f32 -> bf16 into workspace ----
__global__ __launch_bounds__(256)
void feats_to_bf16(const float* __restrict__ in,
                   unsigned short* __restrict__ outp, int ngroups)
{
    int i = blockIdx.x * 256 + threadIdx.x;
    const int stride = gridDim.x * 256;
    for (; i < ngroups; i += stride) {
        const f32x4a a = *(const f32x4a*)(in + (size_t)i * 8);
        const f32x4a b = *(const f32x4a*)(in + (size_t)i * 8 + 4);
        u16x8 t;
#pragma unroll
        for (int j = 0; j < 4; ++j) {
            t[j]     = __builtin_bit_cast(unsigned short, (__bf16)a[j]);
            t[4 + j] = __builtin_bit_cast(unsigned short, (__bf16)b[j]);
        }
        *(u16x8*)(outp + (size_t)i * 8) = t;
    }
}

// ---- shared building blocks (both kernels) ----
#define W_PROLOGUE()                                                        \
    do {                                                                    \
        _Pragma("unroll")                                                   \
        for (int i = 0; i < 7; ++i) {                                       \
            const int s = tid + 1024 * i;                                   \
            if (s < SLOTS) {                                                \
                const int frag = s >> 6;                                    \
                const int ln   = s & 63;                                    \
                const int k    = frag >> 2;                                 \
                const int cc   = (frag >> 1) & 1;                           \
                const int h    = frag & 1;                                  \
                const int co   = (ln & 31) + (h << 5);                      \
                const int cib  = (cc << 4) + ((ln >> 5) << 3);              \
                const float* src = weight + k * 2048 + cib * 64 + co;       \
                u16x8 t;                                                    \
                _Pragma("unroll")                                           \
                for (int j = 0; j < 8; ++j)                                 \
                    t[j] = __builtin_bit_cast(unsigned short,               \
                                              (__bf16)src[j * 64]);         \
                *(u16x8*)&wlds[s * 8] = t;                                  \
            }                                                               \
        }                                                                   \
    } while (0)

#define NBR_PRELOAD()                                                       \
    i32x4u nA[6]; i32x2u nB; int nC;                                        \
    do {                                                                    \
        const int* p = nbr + (size_t)min(row, n - 1) * KV;                  \
        _Pragma("unroll")                                                   \
        for (int qq = 0; qq < 6; ++qq) nA[qq] = *(const i32x4u*)(p + 4*qq); \
        nB = *(const i32x2u*)(p + 24);                                      \
        nC = p[26];                                                         \
        if (!rv) {                                                          \
            _Pragma("unroll")                                               \
            for (int qq = 0; qq < 6; ++qq) nA[qq] = i32x4u{n, n, n, n};     \
            nB = i32x2u{n, n};                                              \
            nC = n;                                                         \
        }                                                                   \
    } while (0)

#define EPILOGUE()                                                          \
    do {                                                                    \
        const float bb0 = bias[l31];                                        \
        const float bb1 = bias[l31 + 32];                                   \
        _Pragma("unroll")                                                   \
        for (int t = 0; t < 16; ++t) {                                      \
            const int rr   = (t & 3) + ((t >> 2) << 3) + (e5 << 2);         \
            const int orow = rb + rr;                                       \
            if (orow < n) {                                                 \
                out[(size_t)orow * COUT + l31]      = acc0[t] + bb0;        \
                out[(size_t)orow * COUT + l31 + 32] = acc1[t] + bb1;        \
            }                                                               \
        }                                                                   \
    } while (0)

// B-fragment register load: 4 x ds_read_b128 for offset kk
#define LDB(kk, B0, B1, B2, B3)                                             \
    do {                                                                    \
        const int fb_ = ((kk) << 2) * 512 + lane * 8;                       \
        B0 = *(const bf16x8*)&wlds[fb_];                                    \
        B1 = *(const bf16x8*)&wlds[fb_ + 512];                              \
        B2 = *(const bf16x8*)&wlds[fb_ + 1024];                             \
        B3 = *(const bf16x8*)&wlds[fb_ + 1536];                             \
    } while (0)

// ---- main kernel: bf16 gathers, depth-3 A-pipeline, B reg double-buffer ----
__global__ __launch_bounds__(1024, 4)
void spconv_mfma_bf16(const unsigned short* __restrict__ fbf16,
                      const float* __restrict__ weight,
                      const float* __restrict__ bias,
                      const int*   __restrict__ nbr,
                      float*       __restrict__ out,
                      int n, int nwg)
{
    __shared__ __align__(16) unsigned short wlds[NFRAG * 512];  // 108 KiB

    const int tid  = threadIdx.x;
    const int lane = tid & 63;
    const int wv   = tid >> 6;
    const int l31  = lane & 31;
    const int e5   = lane >> 5;

    W_PROLOGUE();
    __syncthreads();

    const int q    = nwg >> 3, r = nwg & 7;
    const int xcd  = blockIdx.x & 7, bidx = blockIdx.x >> 3;
    const int wg   = (xcd < r ? xcd * (q + 1) : r * (q + 1) + (xcd - r) * q) + bidx;

    const int rb = wg * RPB + wv * RPW;
    if (rb >= n) return;

    // SRSRC over bf16 features: 64 B/row; sentinel row n -> OOB -> zeros
    i32x4 rsrc;
    rsrc.x = (int)(unsigned)(uintptr_t)fbf16;
    rsrc.y = (int)((uintptr_t)fbf16 >> 32);
    rsrc.z = n * (int)(CIN * sizeof(unsigned short));
    rsrc.w = 0x00020000;

    const int  row = rb + l31;
    const bool rv  = row < n;
    NBR_PRELOAD();

    f32x16 acc0 = {}, acc1 = {};

#define GK(kk, P0, P1)                                                     \
    do {                                                                   \
        const int vo_ = (NIDX(nA, nB, nC, (kk)) << 6) + (e5 << 4);         \
        LOADD(P0, P1, vo_, rsrc);                                          \
    } while (0)

    // A: 4 static mod-4 stages; lane's 16B load IS the A-fragment
    bf16x8 A0a, A0b, A1a, A1b, A2a, A2b, A3a, A3b;
    GK(0, A0a, A0b);
    GK(1, A1a, A1b);
    GK(2, A2a, A2b);

    // B: static even/odd double buffer, k=0 preloaded
    bf16x8 be0, be1, be2, be3, bo0, bo1, bo2, bo3;
    LDB(0, be0, be1, be2, be3);

#define KSTEP(CA, CB, PA, PB)                                              \
    do {                                                                   \
        if (k + 3 < KV)       { GK(k + 3, PA, PB); WAIT6(CA, CB); }        \
        else if (k + 3 == KV) { WAIT4(CA, CB); }                           \
        else if (k + 2 == KV) { WAIT2(CA, CB); }                           \
        else                  { WAIT0(CA, CB); }                           \
    } while (0)

#pragma unroll
    for (int k = 0; k < KV; ++k) {
        bf16x8 x0, x1;
        if ((k & 3) == 0)      { KSTEP(A0a, A0b, A3a, A3b); x0 = A0a; x1 = A0b; }
        else if ((k & 3) == 1) { KSTEP(A1a, A1b, A0a, A0b); x0 = A1a; x1 = A1b; }
        else if ((k & 3) == 2) { KSTEP(A2a, A2b, A1a, A1b); x0 = A2a; x1 = A2b; }
        else                   { KSTEP(A3a, A3b, A2a, A2b); x0 = A3a; x1 = A3b; }

        // issue k+1's B reads into the other buffer, THEN consume this
        // buffer (its reads were issued one full body ago -> lgkm stall ~0)
        if ((k & 1) == 0) {
            if (k + 1 < KV) LDB(k + 1, bo0, bo1, bo2, bo3);
            acc0 = __builtin_amdgcn_mfma_f32_32x32x16_bf16(x0, be0, acc0, 0, 0, 0);
            acc1 = __builtin_amdgcn_mfma_f32_32x32x16_bf16(x0, be1, acc1, 0, 0, 0);
            acc0 = __builtin_amdgcn_mfma_f32_32x32x16_bf16(x1, be2, acc0, 0, 0, 0);
            acc1 = __builtin_amdgcn_mfma_f32_32x32x16_bf16(x1, be3, acc1, 0, 0, 0);
        } else {
            if (k + 1 < KV) LDB(k + 1, be0, be1, be2, be3);
            acc0 = __builtin_amdgcn_mfma_f32_32x32x16_bf16(x0, bo0, acc0, 0, 0, 0);
            acc1 = __builtin_amdgcn_mfma_f32_32x32x16_bf16(x0, bo1, acc1, 0, 0, 0);
            acc0 = __builtin_amdgcn_mfma_f32_32x32x16_bf16(x1, bo2, acc0, 0, 0, 0);
            acc1 = __builtin_amdgcn_mfma_f32_32x32x16_bf16(x1, bo3, acc1, 0, 0, 0);
        }
    }
#undef KSTEP
#undef GK

    EPILOGUE();
}

// ---- fallback kernel (R9, verified): f32 gathers, depth-1 ----
__global__ __launch_bounds__(1024, 4)
void spconv_mfma_f32g(const float* __restrict__ feats,
                      const float* __restrict__ weight,
                      const float* __restrict__ bias,
                      const int*   __restrict__ nbr,
                      float*       __restrict__ out,
                      int n, int nwg)
{
    __shared__ __align__(16) unsigned short wlds[NFRAG * 512];  // 108 KiB

    const int tid  = threadIdx.x;
    const int lane = tid & 63;
    const int wv   = tid >> 6;
    const int l31  = lane & 31;
    const int e5   = lane >> 5;

    W_PROLOGUE();
    __syncthreads();

    const int q    = nwg >> 3, r = nwg & 7;
    const int xcd  = blockIdx.x & 7, bidx = blockIdx.x >> 3;
    const int wg   = (xcd < r ? xcd * (q + 1) : r * (q + 1) + (xcd - r) * q) + bidx;

    const int rb = wg * RPB + wv * RPW;
    if (rb >= n) return;

    i32x4 rsrc;
    rsrc.x = (int)(unsigned)(uintptr_t)feats;
    rsrc.y = (int)((uintptr_t)feats >> 32);
    rsrc.z = n * (int)(CIN * sizeof(float));
    rsrc.w = 0x00020000;

    const int  row = rb + l31;
    const bool rv  = row < n;
    NBR_PRELOAD();

    f32x16 acc0 = {}, acc1 = {};

#define GATHER_K(kk, B0, B1, B2, B3)                                      \
    do {                                                                  \
        const int voff_ = (NIDX(nA, nB, nC, (kk)) << 7) + (e5 << 5);      \
        LOADQ(B0, B1, B2, B3, voff_, rsrc);                               \
    } while (0)

    f32x4a pa0, pa1, pa2, pa3, pb0, pb1, pb2, pb3;
    GATHER_K(0, pa0, pa1, pa2, pa3);
#pragma unroll
    for (int k = 0; k < KV; ++k) {
        const int fb = (k << 2) * 512 + lane * 8;
        const bf16x8 b00 = *(const bf16x8*)&wlds[fb];
        const bf16x8 b01 = *(const bf16x8*)&wlds[fb + 512];
        const bf16x8 b10 = *(const bf16x8*)&wlds[fb + 1024];
        const bf16x8 b11 = *(const bf16x8*)&wlds[fb + 1536];

        bf16x8 x0, x1;
        if ((k & 1) == 0) {
            if (k + 1 < KV) { GATHER_K(k + 1, pb0, pb1, pb2, pb3); WAITV4(pa0, pa1, pa2, pa3); }
            else            { WAITV0(pa0, pa1, pa2, pa3); }
            x0 = cvt8(pa0, pa1); x1 = cvt8(pa2, pa3);
        } else {
            if (k + 1 < KV) { GATHER_K(k + 1, pa0, pa1, pa2, pa3); WAITV4(pb0, pb1, pb2, pb3); }
            else            { WAITV0(pb0, pb1, pb2, pb3); }
            x0 = cvt8(pb0, pb1); x1 = cvt8(pb2, pb3);
        }

        acc0 = __builtin_amdgcn_mfma_f32_32x32x16_bf16(x0, b00, acc0, 0, 0, 0);
        acc1 = __builtin_amdgcn_mfma_f32_32x32x16_bf16(x0, b01, acc1, 0, 0, 0);
        acc0 = __builtin_amdgcn_mfma_f32_32x32x16_bf16(x1, b10, acc0, 0, 0, 0);
        acc1 = __builtin_amdgcn_mfma_f32_32x32x16_bf16(x1, b11, acc1, 0, 0, 0);
    }
#undef GATHER_K

    EPILOGUE();
}

extern "C" void kernel_launch(void* const* d_in, const int* in_sizes, int n_in,
                              void* d_out, int out_size, void* d_ws, size_t ws_size,
                              hipStream_t stream)
{
    const float* feats  = (const float*)d_in[0];   // (N, 32) f32
    const float* weight = (const float*)d_in[1];   // (27, 32, 64) f32
    const float* bias   = (const float*)d_in[2];   // (64,) f32
    const int*   nbr    = (const int*)  d_in[3];   // (N, 27) i32, sentinel = N

    float* out = (float*)d_out;                    // (N, 64) f32

    const int n   = in_sizes[0] / CIN;
    const int nwg = (n + RPB - 1) / RPB;

    const size_t need = (size_t)n * CIN * sizeof(unsigned short);
    if (ws_size >= need) {
        unsigned short* fbf16 = (unsigned short*)d_ws;
        const int ngroups = n * CIN / 8;
        feats_to_bf16<<<dim3(2048), dim3(256), 0, stream>>>(feats, fbf16, ngroups);
        spconv_mfma_bf16<<<dim3(nwg), dim3(1024), 0, stream>>>(
            fbf16, weight, bias, nbr, out, n, nwg);
    } else {
        spconv_mfma_f32g<<<dim3(nwg), dim3(1024), 0, stream>>>(
            feats, weight, bias, nbr, out, n, nwg);
    }
}